// Round 4
// baseline (136.132 us; speedup 1.0000x reference)
//
#include <hip/hip_runtime.h>
#include <hip/hip_bf16.h>

// MultiHeadAttention: x(16,512,256) f32; mask(1,16,512,512) bool; adj(1,16,512,512) f32;
// Wq/Wk/Wv (256,256) f32.  out = softmax(QK^T/sqrt(64) + adj, mask) @ V + x, f32.
// Plan: kernel1 detect mask dtype; kernel2 QKV projection (bf16 MFMA) -> ws;
//       kernel3 fused attention per (b, h, 64-q-row block), K/V staged in LDS.

#define NB 16
#define NA 512
#define HID 256
#define NHEAD 8
#define DH 32
#define INV_TP 0.125f  // 1/sqrt(2*32)

typedef __attribute__((ext_vector_type(8))) short short8;   // 8 bf16 MFMA frag
typedef __attribute__((ext_vector_type(4))) float floatx4;  // MFMA acc

__device__ __forceinline__ unsigned short f2bf(float f) {
  unsigned int u = __builtin_bit_cast(unsigned int, f);
  u += 0x7fffu + ((u >> 16) & 1u);  // round-to-nearest-even
  return (unsigned short)(u >> 16);
}

__device__ __forceinline__ floatx4 mfma16(short8 a, short8 b, floatx4 c) {
  return __builtin_amdgcn_mfma_f32_16x16x32_bf16(a, b, c, 0, 0, 0);
}

__device__ __forceinline__ short8 ld8f32_bf16(const float* __restrict__ p) {
  float4 a = *(const float4*)p;
  float4 b = *(const float4*)(p + 4);
  short8 r;
  r[0] = (short)f2bf(a.x); r[1] = (short)f2bf(a.y);
  r[2] = (short)f2bf(a.z); r[3] = (short)f2bf(a.w);
  r[4] = (short)f2bf(b.x); r[5] = (short)f2bf(b.y);
  r[6] = (short)f2bf(b.z); r[7] = (short)f2bf(b.w);
  return r;
}

// Mask may arrive as 1-byte bool or normalized int32; detect from byte pattern.
// First 1024 uint32: bool(0/1 bytes) -> ~960 nonzero; int32(0/1) -> ~512.
__global__ void detect_mask_kernel(const unsigned int* __restrict__ m,
                                   int* __restrict__ flag) {
  __shared__ int cnt[256];
  int t = threadIdx.x, c = 0;
  for (int i = t; i < 1024; i += 256) c += (m[i] != 0u) ? 1 : 0;
  cnt[t] = c;
  __syncthreads();
  for (int s = 128; s > 0; s >>= 1) {
    if (t < s) cnt[t] += cnt[t + s];
    __syncthreads();
  }
  if (t == 0) *flag = (cnt[0] > 736) ? 1 : 0;  // 1 => bytes, 0 => int32
}

// Y[m][c] = sum_k X[m][k] * W[c][k]; store bf16 as [b][h][n][d].
// grid: (128 row-tiles of 64, 3 weights), block 256 (4 waves, each 64 rows x 64 cols).
__global__ __launch_bounds__(256) void qkv_proj(
    const float* __restrict__ X, const float* __restrict__ Wq,
    const float* __restrict__ Wk, const float* __restrict__ Wv,
    unsigned short* __restrict__ Y) {
  const float* W = (blockIdx.y == 0) ? Wq : (blockIdx.y == 1) ? Wk : Wv;
  unsigned short* Yo = Y + (size_t)blockIdx.y * (NB * NHEAD * NA * DH);
  const int wave = threadIdx.x >> 6, lane = threadIdx.x & 63;
  const int lr = lane & 15, lh = lane >> 4;
  const int m0 = blockIdx.x * 64;
  const int cb = wave * 64;
  const floatx4 z = {0.f, 0.f, 0.f, 0.f};
  floatx4 acc[4][4];
#pragma unroll
  for (int i = 0; i < 4; i++)
#pragma unroll
    for (int j = 0; j < 4; j++) acc[i][j] = z;

  for (int kb = 0; kb < HID; kb += 32) {
    short8 a[4], bw[4];
#pragma unroll
    for (int rt = 0; rt < 4; rt++)
      a[rt] = ld8f32_bf16(X + (size_t)(m0 + rt * 16 + lr) * HID + kb + lh * 8);
#pragma unroll
    for (int ci = 0; ci < 4; ci++)
      bw[ci] = ld8f32_bf16(W + (size_t)(cb + ci * 16 + lr) * HID + kb + lh * 8);
#pragma unroll
    for (int rt = 0; rt < 4; rt++)
#pragma unroll
      for (int ci = 0; ci < 4; ci++)
        acc[rt][ci] = mfma16(a[rt], bw[ci], acc[rt][ci]);
  }
#pragma unroll
  for (int rt = 0; rt < 4; rt++)
#pragma unroll
    for (int ci = 0; ci < 4; ci++)
#pragma unroll
      for (int r = 0; r < 4; r++) {
        int m = m0 + rt * 16 + lh * 4 + r;   // D layout: row=(l>>4)*4+reg
        int c = cb + ci * 16 + lr;           //           col=l&15
        int bb = m >> 9, n = m & 511, hh = c >> 5, dd = c & 31;
        Yo[((size_t)(bb * NHEAD + hh) * NA + n) * DH + dd] = f2bf(acc[rt][ci][r]);
      }
}

// grid: (8 q-blocks, 8 heads, 16 batch), block 256 (4 waves x 16 q-rows).
// LDS: K[512][40] + Vt[32][520] + alpha[4][16][520] = 137.5 KB.
__global__ __launch_bounds__(256, 1) void attn_fused(
    const unsigned short* __restrict__ Qw, const unsigned short* __restrict__ Kw,
    const unsigned short* __restrict__ Vw, const float* __restrict__ X,
    const unsigned char* __restrict__ maskB, const int* __restrict__ maskI,
    const float* __restrict__ adj, const int* __restrict__ flag,
    float* __restrict__ out) {
  __shared__ __align__(16) unsigned short Klds[NA * 40];
  __shared__ __align__(16) unsigned short Vt[DH * 520];
  __shared__ __align__(16) unsigned short Alds[4 * 16 * 520];
  const int qb = blockIdx.x, h = blockIdx.y, b = blockIdx.z;
  const int t = threadIdx.x;
  const size_t bh = (size_t)(b * NHEAD + h) * NA * DH;
  const unsigned short* Kg = Kw + bh;
  const unsigned short* Vg = Vw + bh;

  // stage K (row-major, rows padded to 40 bf16 = conflict-light, 16B-aligned)
  for (int c = t; c < NA * 4; c += 256) {
    int key = c >> 2, kk = (c & 3) * 8;
    *(uint4*)&Klds[key * 40 + kk] = *(const uint4*)&Kg[key * DH + kk];
  }
  // stage V transposed: Vt[d][key], rows padded to 520
  for (int c = t; c < NA * 4; c += 256) {
    int key = c >> 2, dc = (c & 3) * 8;
    uint4 v = *(const uint4*)&Vg[key * DH + dc];
    Vt[(dc + 0) * 520 + key] = (unsigned short)(v.x & 0xffffu);
    Vt[(dc + 1) * 520 + key] = (unsigned short)(v.x >> 16);
    Vt[(dc + 2) * 520 + key] = (unsigned short)(v.y & 0xffffu);
    Vt[(dc + 3) * 520 + key] = (unsigned short)(v.y >> 16);
    Vt[(dc + 4) * 520 + key] = (unsigned short)(v.z & 0xffffu);
    Vt[(dc + 5) * 520 + key] = (unsigned short)(v.z >> 16);
    Vt[(dc + 6) * 520 + key] = (unsigned short)(v.w & 0xffffu);
    Vt[(dc + 7) * 520 + key] = (unsigned short)(v.w >> 16);
  }
  __syncthreads();

  const int wave = t >> 6, lane = t & 63, lr = lane & 15, lh = lane >> 4;
  const int q0 = qb * 64 + wave * 16;

  // S^T = K * Q^T : D[key_local][q_local]; lane holds col q=lr, rows key=lh*4+r (+16*kt)
  short8 qf = *(const short8*)&Qw[bh + (size_t)(q0 + lr) * DH + lh * 8];
  const floatx4 z = {0.f, 0.f, 0.f, 0.f};
  floatx4 s[32];
#pragma unroll
  for (int kt = 0; kt < 32; kt++) s[kt] = z;
#pragma unroll
  for (int kt = 0; kt < 32; kt++) {
    short8 kf = *(const short8*)&Klds[(kt * 16 + lr) * 40 + lh * 8];
    s[kt] = mfma16(kf, qf, s[kt]);
  }

  const int q = q0 + lr;
  const size_t rowoff = ((size_t)b * NA + q) * NA;
  const float* adjRow = adj + rowoff;
  const bool mBytes = (*flag != 0);

  float mmax = -3.0e38f;
#pragma unroll
  for (int kt = 0; kt < 32; kt++) {
    const int k0 = kt * 16 + lh * 4;  // 4 consecutive keys per lane
    float4 av = *(const float4*)&adjRow[k0];
    float v0 = s[kt][0] * INV_TP + av.x;
    float v1 = s[kt][1] * INV_TP + av.y;
    float v2 = s[kt][2] * INV_TP + av.z;
    float v3 = s[kt][3] * INV_TP + av.w;
    if (mBytes) {
      uchar4 mb = *(const uchar4*)&maskB[rowoff + k0];
      if (mb.x) v0 = -1e30f;
      if (mb.y) v1 = -1e30f;
      if (mb.z) v2 = -1e30f;
      if (mb.w) v3 = -1e30f;
    } else {
      int4 mi = *(const int4*)&maskI[rowoff + k0];
      if (mi.x) v0 = -1e30f;
      if (mi.y) v1 = -1e30f;
      if (mi.z) v2 = -1e30f;
      if (mi.w) v3 = -1e30f;
    }
    s[kt][0] = v0; s[kt][1] = v1; s[kt][2] = v2; s[kt][3] = v3;
    mmax = fmaxf(mmax, fmaxf(fmaxf(v0, v1), fmaxf(v2, v3)));
  }
  // row q lives in lanes {lr, lr+16, lr+32, lr+48}
  mmax = fmaxf(mmax, __shfl_xor(mmax, 16));
  mmax = fmaxf(mmax, __shfl_xor(mmax, 32));

  float sum = 0.f;
#pragma unroll
  for (int kt = 0; kt < 32; kt++) {
    float e0 = __expf(s[kt][0] - mmax);
    float e1 = __expf(s[kt][1] - mmax);
    float e2 = __expf(s[kt][2] - mmax);
    float e3 = __expf(s[kt][3] - mmax);
    s[kt][0] = e0; s[kt][1] = e1; s[kt][2] = e2; s[kt][3] = e3;
    sum += (e0 + e1) + (e2 + e3);
  }
  sum += __shfl_xor(sum, 16);
  sum += __shfl_xor(sum, 32);
  const float inv = 1.0f / sum;

  // alpha^T -> LDS as alpha[q_local][key] bf16 (4 keys packed per 8B write)
  unsigned short* arow = &Alds[(wave * 16 + lr) * 520];
#pragma unroll
  for (int kt = 0; kt < 32; kt++) {
    ushort4 w;
    w.x = f2bf(s[kt][0] * inv);
    w.y = f2bf(s[kt][1] * inv);
    w.z = f2bf(s[kt][2] * inv);
    w.w = f2bf(s[kt][3] * inv);
    *(ushort4*)&arow[kt * 16 + lh * 4] = w;
  }
  __syncthreads();

  // PV: attn[q][d] = sum_key alpha[q][key] * V[key][d]
  floatx4 o0 = z, o1 = z;
  const unsigned short* abase = &Alds[(wave * 16 + lr) * 520];
#pragma unroll
  for (int kc = 0; kc < 16; kc++) {
    short8 af = *(const short8*)&abase[kc * 32 + lh * 8];
    short8 v0 = *(const short8*)&Vt[lr * 520 + kc * 32 + lh * 8];
    short8 v1 = *(const short8*)&Vt[(16 + lr) * 520 + kc * 32 + lh * 8];
    o0 = mfma16(af, v0, o0);
    o1 = mfma16(af, v1, o1);
  }
#pragma unroll
  for (int r = 0; r < 4; r++) {
    size_t idx = ((size_t)b * NA + (q0 + lh * 4 + r)) * HID + h * DH + lr;
    out[idx] = o0[r] + X[idx];
    out[idx + 16] = o1[r] + X[idx + 16];
  }
}

extern "C" void kernel_launch(void* const* d_in, const int* in_sizes, int n_in,
                              void* d_out, int out_size, void* d_ws, size_t ws_size,
                              hipStream_t stream) {
  const float* x = (const float*)d_in[0];
  const void* mask = d_in[1];
  const float* adj = (const float*)d_in[2];
  const float* Wq = (const float*)d_in[3];
  const float* Wk = (const float*)d_in[4];
  const float* Wv = (const float*)d_in[5];
  float* out = (float*)d_out;

  char* ws = (char*)d_ws;
  int* flag = (int*)ws;
  unsigned short* Qw = (unsigned short*)(ws + 4096);                 // 4 MB
  unsigned short* Kw = (unsigned short*)(ws + 4096 + 4194304);      // 4 MB
  unsigned short* Vw = (unsigned short*)(ws + 4096 + 2 * 4194304); // 4 MB
  // requires ws_size >= ~12.6 MB

  detect_mask_kernel<<<1, 256, 0, stream>>>((const unsigned int*)mask, flag);
  qkv_proj<<<dim3(128, 3), 256, 0, stream>>>(x, Wq, Wk, Wv, Qw);
  attn_fused<<<dim3(8, NHEAD, NB), 256, 0, stream>>>(
      Qw, Kw, Vw, x, (const unsigned char*)mask, (const int*)mask, adj, flag, out);
}

// Round 5
// 105.970 us; speedup vs baseline: 1.2846x; 1.2846x over previous
//
#include <hip/hip_runtime.h>
#include <hip/hip_bf16.h>

// MultiHeadAttention: x(16,512,256) f32; mask(1,16,512,512) bool; adj(1,16,512,512) f32;
// Wq/Wk/Wv (256,256) f32.  out = softmax(QK^T/sqrt(64) + adj, mask) @ V + x, f32.
// R4: removed Alds alpha round-trip via PV K-dim relabeling (A/B share any slot->key
// bijection); LDS 137.5KB -> 72.5KB -> 2 blocks/CU (occupancy 11% -> ~22%).

#define NB 16
#define NA 512
#define HID 256
#define NHEAD 8
#define DH 32
#define INV_TP 0.125f  // 1/sqrt(2*32)

typedef __attribute__((ext_vector_type(8))) short short8;   // 8 bf16 MFMA frag
typedef __attribute__((ext_vector_type(4))) float floatx4;  // MFMA acc

__device__ __forceinline__ unsigned short f2bf(float f) {
  unsigned int u = __builtin_bit_cast(unsigned int, f);
  u += 0x7fffu + ((u >> 16) & 1u);  // round-to-nearest-even
  return (unsigned short)(u >> 16);
}

__device__ __forceinline__ floatx4 mfma16(short8 a, short8 b, floatx4 c) {
  return __builtin_amdgcn_mfma_f32_16x16x32_bf16(a, b, c, 0, 0, 0);
}

__device__ __forceinline__ short8 ld8f32_bf16(const float* __restrict__ p) {
  float4 a = *(const float4*)p;
  float4 b = *(const float4*)(p + 4);
  short8 r;
  r[0] = (short)f2bf(a.x); r[1] = (short)f2bf(a.y);
  r[2] = (short)f2bf(a.z); r[3] = (short)f2bf(a.w);
  r[4] = (short)f2bf(b.x); r[5] = (short)f2bf(b.y);
  r[6] = (short)f2bf(b.z); r[7] = (short)f2bf(b.w);
  return r;
}

// Mask may arrive as 1-byte bool or normalized int32; detect from byte pattern.
__global__ void detect_mask_kernel(const unsigned int* __restrict__ m,
                                   int* __restrict__ flag) {
  __shared__ int cnt[256];
  int t = threadIdx.x, c = 0;
  for (int i = t; i < 1024; i += 256) c += (m[i] != 0u) ? 1 : 0;
  cnt[t] = c;
  __syncthreads();
  for (int s = 128; s > 0; s >>= 1) {
    if (t < s) cnt[t] += cnt[t + s];
    __syncthreads();
  }
  if (t == 0) *flag = (cnt[0] > 736) ? 1 : 0;  // 1 => bytes, 0 => int32
}

// Y[m][c] = sum_k X[m][k] * W[c][k]; store bf16 as [b][h][n][d].
__global__ __launch_bounds__(256) void qkv_proj(
    const float* __restrict__ X, const float* __restrict__ Wq,
    const float* __restrict__ Wk, const float* __restrict__ Wv,
    unsigned short* __restrict__ Y) {
  const float* W = (blockIdx.y == 0) ? Wq : (blockIdx.y == 1) ? Wk : Wv;
  unsigned short* Yo = Y + (size_t)blockIdx.y * (NB * NHEAD * NA * DH);
  const int wave = threadIdx.x >> 6, lane = threadIdx.x & 63;
  const int lr = lane & 15, lh = lane >> 4;
  const int m0 = blockIdx.x * 64;
  const int cb = wave * 64;
  const floatx4 z = {0.f, 0.f, 0.f, 0.f};
  floatx4 acc[4][4];
#pragma unroll
  for (int i = 0; i < 4; i++)
#pragma unroll
    for (int j = 0; j < 4; j++) acc[i][j] = z;

  for (int kb = 0; kb < HID; kb += 32) {
    short8 a[4], bw[4];
#pragma unroll
    for (int rt = 0; rt < 4; rt++)
      a[rt] = ld8f32_bf16(X + (size_t)(m0 + rt * 16 + lr) * HID + kb + lh * 8);
#pragma unroll
    for (int ci = 0; ci < 4; ci++)
      bw[ci] = ld8f32_bf16(W + (size_t)(cb + ci * 16 + lr) * HID + kb + lh * 8);
#pragma unroll
    for (int rt = 0; rt < 4; rt++)
#pragma unroll
      for (int ci = 0; ci < 4; ci++)
        acc[rt][ci] = mfma16(a[rt], bw[ci], acc[rt][ci]);
  }
#pragma unroll
  for (int rt = 0; rt < 4; rt++)
#pragma unroll
    for (int ci = 0; ci < 4; ci++)
#pragma unroll
      for (int r = 0; r < 4; r++) {
        int m = m0 + rt * 16 + lh * 4 + r;   // D layout: row=(l>>4)*4+reg
        int c = cb + ci * 16 + lr;           //           col=l&15
        int bb = m >> 9, n = m & 511, hh = c >> 5, dd = c & 31;
        Yo[((size_t)(bb * NHEAD + hh) * NA + n) * DH + dd] = f2bf(acc[rt][ci][r]);
      }
}

// grid: (8 q-blocks, 8 heads, 16 batch), block 256 (4 waves x 16 q-rows).
// LDS: K[512][40] + Vt[32][520] = 72.5 KB -> 2 blocks/CU.
__global__ __launch_bounds__(256, 2) void attn_fused(
    const unsigned short* __restrict__ Qw, const unsigned short* __restrict__ Kw,
    const unsigned short* __restrict__ Vw, const float* __restrict__ X,
    const unsigned char* __restrict__ maskB, const int* __restrict__ maskI,
    const float* __restrict__ adj, const int* __restrict__ flag,
    float* __restrict__ out) {
  __shared__ __align__(16) unsigned short Klds[NA * 40];  // 40960 B
  __shared__ __align__(16) unsigned short Vt[DH * 520];   // 33280 B
  const int qb = blockIdx.x, h = blockIdx.y, b = blockIdx.z;
  const int t = threadIdx.x;
  const size_t bh = (size_t)(b * NHEAD + h) * NA * DH;
  const unsigned short* Kg = Kw + bh;
  const unsigned short* Vg = Vw + bh;

  // stage K (row-major, rows padded to 40 bf16: 2-way max aliasing, 16B-aligned)
  for (int c = t; c < NA * 4; c += 256) {
    int key = c >> 2, kk = (c & 3) * 8;
    *(uint4*)&Klds[key * 40 + kk] = *(const uint4*)&Kg[key * DH + kk];
  }
  // stage V transposed: Vt[d][key], rows padded to 520
  for (int c = t; c < NA * 4; c += 256) {
    int key = c >> 2, dc = (c & 3) * 8;
    uint4 v = *(const uint4*)&Vg[key * DH + dc];
    Vt[(dc + 0) * 520 + key] = (unsigned short)(v.x & 0xffffu);
    Vt[(dc + 1) * 520 + key] = (unsigned short)(v.x >> 16);
    Vt[(dc + 2) * 520 + key] = (unsigned short)(v.y & 0xffffu);
    Vt[(dc + 3) * 520 + key] = (unsigned short)(v.y >> 16);
    Vt[(dc + 4) * 520 + key] = (unsigned short)(v.z & 0xffffu);
    Vt[(dc + 5) * 520 + key] = (unsigned short)(v.z >> 16);
    Vt[(dc + 6) * 520 + key] = (unsigned short)(v.w & 0xffffu);
    Vt[(dc + 7) * 520 + key] = (unsigned short)(v.w >> 16);
  }
  __syncthreads();

  const int wave = t >> 6, lane = t & 63, lr = lane & 15, lh = lane >> 4;
  const int q0 = qb * 64 + wave * 16;

  // S^T = K * Q^T : D[key_local][q_local]; lane holds col q=lr, rows key=lh*4+r (+16*kt)
  short8 qf = *(const short8*)&Qw[bh + (size_t)(q0 + lr) * DH + lh * 8];
  const floatx4 z = {0.f, 0.f, 0.f, 0.f};
  floatx4 s[32];
#pragma unroll
  for (int kt = 0; kt < 32; kt++) s[kt] = z;
#pragma unroll
  for (int kt = 0; kt < 32; kt++) {
    short8 kf = *(const short8*)&Klds[(kt * 16 + lr) * 40 + lh * 8];
    s[kt] = mfma16(kf, qf, s[kt]);
  }

  const int q = q0 + lr;
  const size_t rowoff = ((size_t)b * NA + q) * NA;
  const float* adjRow = adj + rowoff;
  const bool mBytes = (*flag != 0);

  float mmax = -3.0e38f;
#pragma unroll
  for (int kt = 0; kt < 32; kt++) {
    const int k0 = kt * 16 + lh * 4;  // 4 consecutive keys per lane
    float4 av = *(const float4*)&adjRow[k0];
    float v0 = s[kt][0] * INV_TP + av.x;
    float v1 = s[kt][1] * INV_TP + av.y;
    float v2 = s[kt][2] * INV_TP + av.z;
    float v3 = s[kt][3] * INV_TP + av.w;
    if (mBytes) {
      uchar4 mb = *(const uchar4*)&maskB[rowoff + k0];
      if (mb.x) v0 = -1e30f;
      if (mb.y) v1 = -1e30f;
      if (mb.z) v2 = -1e30f;
      if (mb.w) v3 = -1e30f;
    } else {
      int4 mi = *(const int4*)&maskI[rowoff + k0];
      if (mi.x) v0 = -1e30f;
      if (mi.y) v1 = -1e30f;
      if (mi.z) v2 = -1e30f;
      if (mi.w) v3 = -1e30f;
    }
    s[kt][0] = v0; s[kt][1] = v1; s[kt][2] = v2; s[kt][3] = v3;
    mmax = fmaxf(mmax, fmaxf(fmaxf(v0, v1), fmaxf(v2, v3)));
  }
  // row q lives in lanes {lr, lr+16, lr+32, lr+48}
  mmax = fmaxf(mmax, __shfl_xor(mmax, 16));
  mmax = fmaxf(mmax, __shfl_xor(mmax, 32));

  float sum = 0.f;
#pragma unroll
  for (int kt = 0; kt < 32; kt++) {
    float e0 = __expf(s[kt][0] - mmax);
    float e1 = __expf(s[kt][1] - mmax);
    float e2 = __expf(s[kt][2] - mmax);
    float e3 = __expf(s[kt][3] - mmax);
    s[kt][0] = e0; s[kt][1] = e1; s[kt][2] = e2; s[kt][3] = e3;
    sum += (e0 + e1) + (e2 + e3);
  }
  sum += __shfl_xor(sum, 16);
  sum += __shfl_xor(sum, 32);
  const float inv = 1.0f / sum;

  // PV with relabeled K-dim: slot lh*8+j <-> key 32kc + (j<4 ? lh*4+j : 16+lh*4+j-4).
  // A-frag = lane-local alpha (no shuffle, no LDS round-trip); B-frag = matching V keys.
  floatx4 o0 = z, o1 = z;
  const int kb0 = lh * 4;
#pragma unroll
  for (int kc = 0; kc < 16; kc++) {
    union { short8 s8; unsigned int u[4]; } aa;
    aa.u[0] = (unsigned int)f2bf(s[2 * kc][0] * inv) |
              ((unsigned int)f2bf(s[2 * kc][1] * inv) << 16);
    aa.u[1] = (unsigned int)f2bf(s[2 * kc][2] * inv) |
              ((unsigned int)f2bf(s[2 * kc][3] * inv) << 16);
    aa.u[2] = (unsigned int)f2bf(s[2 * kc + 1][0] * inv) |
              ((unsigned int)f2bf(s[2 * kc + 1][1] * inv) << 16);
    aa.u[3] = (unsigned int)f2bf(s[2 * kc + 1][2] * inv) |
              ((unsigned int)f2bf(s[2 * kc + 1][3] * inv) << 16);
    const int kbase = kc * 32 + kb0;
    union { short8 s8; uint2 u2[2]; } v0f, v1f;
    v0f.u2[0] = *(const uint2*)&Vt[lr * 520 + kbase];
    v0f.u2[1] = *(const uint2*)&Vt[lr * 520 + kbase + 16];
    v1f.u2[0] = *(const uint2*)&Vt[(16 + lr) * 520 + kbase];
    v1f.u2[1] = *(const uint2*)&Vt[(16 + lr) * 520 + kbase + 16];
    o0 = mfma16(aa.s8, v0f.s8, o0);
    o1 = mfma16(aa.s8, v1f.s8, o1);
  }
#pragma unroll
  for (int r = 0; r < 4; r++) {
    size_t idx = ((size_t)b * NA + (q0 + lh * 4 + r)) * HID + h * DH + lr;
    out[idx] = o0[r] + X[idx];
    out[idx + 16] = o1[r] + X[idx + 16];
  }
}

extern "C" void kernel_launch(void* const* d_in, const int* in_sizes, int n_in,
                              void* d_out, int out_size, void* d_ws, size_t ws_size,
                              hipStream_t stream) {
  const float* x = (const float*)d_in[0];
  const void* mask = d_in[1];
  const float* adj = (const float*)d_in[2];
  const float* Wq = (const float*)d_in[3];
  const float* Wk = (const float*)d_in[4];
  const float* Wv = (const float*)d_in[5];
  float* out = (float*)d_out;

  char* ws = (char*)d_ws;
  int* flag = (int*)ws;
  unsigned short* Qw = (unsigned short*)(ws + 4096);                 // 4 MB
  unsigned short* Kw = (unsigned short*)(ws + 4096 + 4194304);      // 4 MB
  unsigned short* Vw = (unsigned short*)(ws + 4096 + 2 * 4194304); // 4 MB
  // requires ws_size >= ~12.6 MB

  detect_mask_kernel<<<1, 256, 0, stream>>>((const unsigned int*)mask, flag);
  qkv_proj<<<dim3(128, 3), 256, 0, stream>>>(x, Wq, Wk, Wv, Qw);
  attn_fused<<<dim3(8, NHEAD, NB), 256, 0, stream>>>(
      Qw, Kw, Vw, x, (const unsigned char*)mask, (const int*)mask, adj, flag, out);
}